// Round 4
// baseline (180.519 us; speedup 1.0000x reference)
//
#include <hip/hip_runtime.h>

#define DIM 64
#define NB 4096
#define NTOK 32
#define NL 2

typedef __attribute__((ext_vector_type(8))) __bf16 bf16x8;
typedef __attribute__((ext_vector_type(4))) float f32x4;

__device__ __forceinline__ f32x4 mfma16(bf16x8 a, bf16x8 b, f32x4 c) {
  return __builtin_amdgcn_mfma_f32_16x16x32_bf16(a, b, c, 0, 0, 0);
}

// ws layout (bf16 elems): [0,24576) weights-T, [24576, 24576+6.4M) ent bf16,
// then 2048 rel bf16.
#define WT_OFF   0
#define ENTB_OFF 24576
#define RELB_OFF (24576 + 100000 * 64)
#define WS_NEED_BYTES ((size_t)(RELB_OFF + 2048) * 2)

// Transpose weights to bf16 [col][k] + convert rel table.
__global__ void prep_w(const float* __restrict__ W1, const float* __restrict__ G1,
                       const float* __restrict__ W2, const float* __restrict__ G2,
                       const float* __restrict__ rel, __bf16* __restrict__ ws,
                       int do_rel) {
  int i = blockIdx.x * 256 + threadIdx.x;
  if (i < 8192) {
    int c = i >> 7, k = i & 127;
    ws[i]        = (__bf16)W1[k * 64 + c];
    ws[8192 + i] = (__bf16)G1[k * 64 + c];
  } else if (i < 12288) {
    int j = i - 8192;
    int c = j >> 6, k = j & 63;
    ws[16384 + j] = (__bf16)W2[k * 64 + c];
    ws[20480 + j] = (__bf16)G2[k * 64 + c];
  } else if (do_rel && i < 14336) {
    int j = i - 12288;
    ws[RELB_OFF + j] = (__bf16)rel[j];
  }
}

// Convert ent table f32 -> bf16 (row-major copy). 8 elems/thread.
__global__ void prep_ent(const float* __restrict__ ent, __bf16* __restrict__ entb) {
  int t = blockIdx.x * 256 + threadIdx.x;           // 800000 threads
  const float* src = ent + t * 8;
  f32x4 lo = *(const f32x4*)src;
  f32x4 hi = *(const f32x4*)(src + 4);
  bf16x8 v;
  v[0] = (__bf16)lo[0]; v[1] = (__bf16)lo[1]; v[2] = (__bf16)lo[2]; v[3] = (__bf16)lo[3];
  v[4] = (__bf16)hi[0]; v[5] = (__bf16)hi[1]; v[6] = (__bf16)hi[2]; v[7] = (__bf16)hi[3];
  *(bf16x8*)(entb + t * 8) = v;
}

// One wave = one batch element. LDS only for the GEMM1->GEMM2 transpose
// (wave-private rows) -> no __syncthreads anywhere.
// NOTE register-allocator history: __launch_bounds__(256)      -> 200 VGPR, no
// spill (WRITE 32 KB); (256,3) -> 84 VGPR, 547 MB spill; (256,2) -> 128 VGPR,
// 184 MB spill. The min-waves arg makes clang target a VGPR budget below the
// live accumulator set (128 f32 accs) -> scratch storms. Leave it off.
template <bool BT>
__global__ __launch_bounds__(256) void ckan_main(
    const int* __restrict__ items,
    const int* __restrict__ user_h, const int* __restrict__ user_r, const int* __restrict__ user_t,
    const int* __restrict__ item_h, const int* __restrict__ item_r, const int* __restrict__ item_t,
    const float* __restrict__ ent, const float* __restrict__ rel,
    const __bf16* __restrict__ wsb, const float* __restrict__ w3,
    float* __restrict__ out)
{
  __shared__ __align__(16) __bf16 s1buf[128][72];   // stride 144B: 16B-aligned rows
  __shared__ __align__(16) __bf16 g1buf[128][72];

  const int tid  = threadIdx.x;
  const int w    = tid >> 6;
  const int lane = tid & 63;
  const int b    = blockIdx.x * 4 + w;
  const int r16  = lane & 15;
  const int g4   = lane >> 4;
  const int rb   = w * 32;

  const __bf16* __restrict__ W1t = wsb;
  const __bf16* __restrict__ G1t = wsb + 8192;
  const __bf16* __restrict__ W2t = wsb + 16384;
  const __bf16* __restrict__ G2t = wsb + 20480;
  const __bf16* __restrict__ entb = wsb + ENTB_OFF;
  const __bf16* __restrict__ relb = wsb + RELB_OFF;

  // per-lane w3 columns (constant across all combos)
  float w3c[4];
#pragma unroll
  for (int n = 0; n < 4; ++n) w3c[n] = w3[n * 16 + r16];

  const f32x4 zero4 = {0.f, 0.f, 0.f, 0.f};
  float layer_dot = 0.f;

  for (int l = 0; l < NL; ++l) {
    float uvec[4];
#pragma unroll
    for (int tower = 0; tower < 2; ++tower) {
      const int* __restrict__ Hp = tower ? item_h : user_h;
      const int* __restrict__ Rp = tower ? item_r : user_r;
      const int* __restrict__ Tp = tower ? item_t : user_t;
      const int ibase = (l * NB + b) * NTOK;

      // indices loaded directly (broadcast cache lines; no LDS round-trip)
      const int h0  = Hp[ibase + r16] * DIM;
      const int h1  = Hp[ibase + 16 + r16] * DIM;
      const int rr0 = Rp[ibase + r16] * DIM;
      const int rr1 = Rp[ibase + 16 + r16] * DIM;

      // ---- GEMM1: x[32,128] @ {W1,G1}[128,64] ----
      f32x4 accS[2][4], accG[2][4];
#pragma unroll
      for (int m = 0; m < 2; ++m)
#pragma unroll
        for (int n = 0; n < 4; ++n) { accS[m][n] = zero4; accG[m][n] = zero4; }

#pragma unroll
      for (int kk = 0; kk < 4; ++kk) {
        bf16x8 afr[2];
#pragma unroll
        for (int m = 0; m < 2; ++m) {
          if (BT) {
            const __bf16* src = (kk < 2)
                ? entb + (m ? h1 : h0) + kk * 32 + g4 * 8
                : relb + (m ? rr1 : rr0) + (kk - 2) * 32 + g4 * 8;
            afr[m] = *(const bf16x8*)src;
          } else {
            const float* src = (kk < 2)
                ? ent + (m ? h1 : h0) + kk * 32 + g4 * 8
                : rel + (m ? rr1 : rr0) + (kk - 2) * 32 + g4 * 8;
            f32x4 lo = *(const f32x4*)(src);
            f32x4 hi = *(const f32x4*)(src + 4);
            bf16x8 a;
            a[0] = (__bf16)lo[0]; a[1] = (__bf16)lo[1]; a[2] = (__bf16)lo[2]; a[3] = (__bf16)lo[3];
            a[4] = (__bf16)hi[0]; a[5] = (__bf16)hi[1]; a[6] = (__bf16)hi[2]; a[7] = (__bf16)hi[3];
            afr[m] = a;
          }
        }
#pragma unroll
        for (int n = 0; n < 4; ++n) {
          bf16x8 bS = *(const bf16x8*)(W1t + (n * 16 + r16) * 128 + kk * 32 + g4 * 8);
          bf16x8 bG = *(const bf16x8*)(G1t + (n * 16 + r16) * 128 + kk * 32 + g4 * 8);
#pragma unroll
          for (int m = 0; m < 2; ++m) {
            accS[m][n] = mfma16(afr[m], bS, accS[m][n]);
            accG[m][n] = mfma16(afr[m], bG, accG[m][n]);
          }
        }
      }

      // ReLU + bf16 -> LDS (wave-private rows) for the GEMM2 transpose
#pragma unroll
      for (int m = 0; m < 2; ++m)
#pragma unroll
        for (int n = 0; n < 4; ++n)
#pragma unroll
          for (int i = 0; i < 4; ++i) {
            const int row = rb + m * 16 + g4 * 4 + i;
            const int col = n * 16 + r16;
            s1buf[row][col] = (__bf16)fmaxf(accS[m][n][i], 0.f);
            g1buf[row][col] = (__bf16)fmaxf(accG[m][n][i], 0.f);
          }

      // ---- GEMM2: s1@W2, g1@G2 (K=64) ----
      f32x4 acc2S[2][4], acc2G[2][4];
#pragma unroll
      for (int m = 0; m < 2; ++m)
#pragma unroll
        for (int n = 0; n < 4; ++n) { acc2S[m][n] = zero4; acc2G[m][n] = zero4; }
#pragma unroll
      for (int kk = 0; kk < 2; ++kk) {
        bf16x8 aS[2], aG[2];
#pragma unroll
        for (int m = 0; m < 2; ++m) {
          const int tok = rb + m * 16 + r16;
          aS[m] = *(const bf16x8*)&s1buf[tok][kk * 32 + g4 * 8];
          aG[m] = *(const bf16x8*)&g1buf[tok][kk * 32 + g4 * 8];
        }
#pragma unroll
        for (int n = 0; n < 4; ++n) {
          bf16x8 bS = *(const bf16x8*)(W2t + (n * 16 + r16) * 64 + kk * 32 + g4 * 8);
          bf16x8 bG = *(const bf16x8*)(G2t + (n * 16 + r16) * 64 + kk * 32 + g4 * 8);
#pragma unroll
          for (int m = 0; m < 2; ++m) {
            acc2S[m][n] = mfma16(aS[m], bS, acc2S[m][n]);
            acc2G[m][n] = mfma16(aG[m], bG, acc2G[m][n]);
          }
        }
      }

      // ---- s3/softmax entirely in registers ----
      // lane owns rows m*16+g4*4+i, cols n*16+r16 of s2.
      float att[2][4];
      {
        float dotp[2][4];
#pragma unroll
        for (int m = 0; m < 2; ++m)
#pragma unroll
          for (int i = 0; i < 4; ++i) {
            float d = 0.f;
#pragma unroll
            for (int n = 0; n < 4; ++n)
              d += fmaxf(acc2S[m][n][i], 0.f) * w3c[n];
            dotp[m][i] = d;
          }
        // sum over the 16 lanes of the r16 group -> full row dot
#pragma unroll
        for (int off = 1; off <= 8; off <<= 1)
#pragma unroll
          for (int m = 0; m < 2; ++m)
#pragma unroll
            for (int i = 0; i < 4; ++i)
              dotp[m][i] += __shfl_xor(dotp[m][i], off);
        float mx = -1.f;
#pragma unroll
        for (int m = 0; m < 2; ++m)
#pragma unroll
          for (int i = 0; i < 4; ++i) {
            dotp[m][i] = 1.f / (1.f + __expf(-dotp[m][i]));  // sc
            mx = fmaxf(mx, dotp[m][i]);
          }
        mx = fmaxf(mx, __shfl_xor(mx, 16));
        mx = fmaxf(mx, __shfl_xor(mx, 32));
        float sm = 0.f;
#pragma unroll
        for (int m = 0; m < 2; ++m)
#pragma unroll
          for (int i = 0; i < 4; ++i) {
            att[m][i] = __expf(dotp[m][i] - mx);
            sm += att[m][i];
          }
        sm += __shfl_xor(sm, 16);
        sm += __shfl_xor(sm, 32);
        const float inv = 1.f / sm;
#pragma unroll
        for (int m = 0; m < 2; ++m)
#pragma unroll
          for (int i = 0; i < 4; ++i) att[m][i] *= inv;
      }

      // ---- epilogue: out[d] = sum_t att[t] * 2*sigmoid(g2[t,d]) * t_e[t,d] ----
      float outn[4] = {0.f, 0.f, 0.f, 0.f};
#pragma unroll
      for (int m = 0; m < 2; ++m)
#pragma unroll
        for (int i = 0; i < 4; ++i) {
          const float at = att[m][i];
          const int to = Tp[ibase + m * 16 + g4 * 4 + i] * DIM;
#pragma unroll
          for (int n = 0; n < 4; ++n) {
            const float g2 = 2.f / (1.f + __expf(-acc2G[m][n][i]));
            const float te = BT ? (float)entb[to + n * 16 + r16]
                                : ent[to + n * 16 + r16];
            outn[n] += at * g2 * te;
          }
        }
#pragma unroll
      for (int n = 0; n < 4; ++n) {
        outn[n] += __shfl_xor(outn[n], 16);
        outn[n] += __shfl_xor(outn[n], 32);
      }
      if (tower == 0) {
#pragma unroll
        for (int n = 0; n < 4; ++n) uvec[n] = outn[n];
      } else {
#pragma unroll
        for (int n = 0; n < 4; ++n) layer_dot += uvec[n] * outn[n];
      }
    } // tower
  } // l

  // ---- origins + final score ----
  float uo = 0.f;
  const int ib0 = b * NTOK;
#pragma unroll 8
  for (int t = 0; t < NTOK; ++t) {
    const int ho = user_h[ib0 + t] * DIM + lane;
    uo += BT ? (float)entb[ho] : ent[ho];
  }
  uo *= (1.f / 32.f);
  const int io_o = items[b] * DIM + lane;
  const float io = BT ? (float)entb[io_o] : ent[io_o];
  float part = uo * io + 0.25f * layer_dot;   // layer cols 4x-replicated
#pragma unroll
  for (int off = 32; off >= 1; off >>= 1) part += __shfl_xor(part, off);
  if (lane == 0) out[b] = 1.f / (1.f + __expf(-part));
}

extern "C" void kernel_launch(void* const* d_in, const int* in_sizes, int n_in,
                              void* d_out, int out_size, void* d_ws, size_t ws_size,
                              hipStream_t stream) {
  const int*   items  = (const int*)d_in[1];
  const int*   user_h = (const int*)d_in[2];
  const int*   user_r = (const int*)d_in[3];
  const int*   user_t = (const int*)d_in[4];
  const int*   item_h = (const int*)d_in[5];
  const int*   item_r = (const int*)d_in[6];
  const int*   item_t = (const int*)d_in[7];
  const float* ent    = (const float*)d_in[8];
  const float* rel    = (const float*)d_in[9];
  const float* W1     = (const float*)d_in[10];
  const float* W2     = (const float*)d_in[11];
  const float* w3     = (const float*)d_in[12];
  const float* G1     = (const float*)d_in[13];
  const float* G2     = (const float*)d_in[14];
  __bf16* wsb = (__bf16*)d_ws;
  float* out = (float*)d_out;

  const bool bt = ws_size >= WS_NEED_BYTES;
  prep_w<<<dim3(56), dim3(256), 0, stream>>>(W1, G1, W2, G2, rel, wsb, bt ? 1 : 0);
  if (bt) {
    prep_ent<<<dim3(3125), dim3(256), 0, stream>>>(ent, wsb + ENTB_OFF);
    ckan_main<true><<<dim3(NB / 4), dim3(256), 0, stream>>>(
        items, user_h, user_r, user_t, item_h, item_r, item_t,
        ent, rel, wsb, w3, out);
  } else {
    ckan_main<false><<<dim3(NB / 4), dim3(256), 0, stream>>>(
        items, user_h, user_r, user_t, item_h, item_r, item_t,
        ent, rel, wsb, w3, out);
  }
}

// Round 5
// 172.280 us; speedup vs baseline: 1.0478x; 1.0478x over previous
//
#include <hip/hip_runtime.h>

#define DIM 64
#define NB 4096
#define NTOK 32
#define NL 2

typedef __attribute__((ext_vector_type(8))) __bf16 bf16x8;
typedef __attribute__((ext_vector_type(4))) float f32x4;

__device__ __forceinline__ f32x4 mfma16(bf16x8 a, bf16x8 b, f32x4 c) {
  return __builtin_amdgcn_mfma_f32_16x16x32_bf16(a, b, c, 0, 0, 0);
}

// ws layout (bf16 elems): [0,24576) weights-T, [24576, 24576+6.4M) ent bf16,
// then 2048 rel bf16.
#define ENTB_OFF 24576
#define RELB_OFF (24576 + 100000 * 64)
#define WS_NEED_BYTES ((size_t)(RELB_OFF + 2048) * 2)

// Transpose weights to bf16 [col][k] + convert rel table.
__global__ void prep_w(const float* __restrict__ W1, const float* __restrict__ G1,
                       const float* __restrict__ W2, const float* __restrict__ G2,
                       const float* __restrict__ rel, __bf16* __restrict__ ws,
                       int do_rel) {
  int i = blockIdx.x * 256 + threadIdx.x;
  if (i < 8192) {
    int c = i >> 7, k = i & 127;
    ws[i]        = (__bf16)W1[k * 64 + c];
    ws[8192 + i] = (__bf16)G1[k * 64 + c];
  } else if (i < 12288) {
    int j = i - 8192;
    int c = j >> 6, k = j & 63;
    ws[16384 + j] = (__bf16)W2[k * 64 + c];
    ws[20480 + j] = (__bf16)G2[k * 64 + c];
  } else if (do_rel && i < 14336) {
    int j = i - 12288;
    ws[RELB_OFF + j] = (__bf16)rel[j];
  }
}

// Convert ent table f32 -> bf16 (row-major copy). 8 elems/thread.
__global__ void prep_ent(const float* __restrict__ ent, __bf16* __restrict__ entb) {
  int t = blockIdx.x * 256 + threadIdx.x;           // 800000 threads
  const float* src = ent + t * 8;
  f32x4 lo = *(const f32x4*)src;
  f32x4 hi = *(const f32x4*)(src + 4);
  bf16x8 v;
  v[0] = (__bf16)lo[0]; v[1] = (__bf16)lo[1]; v[2] = (__bf16)lo[2]; v[3] = (__bf16)lo[3];
  v[4] = (__bf16)hi[0]; v[5] = (__bf16)hi[1]; v[6] = (__bf16)hi[2]; v[7] = (__bf16)hi[3];
  *(bf16x8*)(entb + t * 8) = v;
}

// One BLOCK = one batch element; its 4 waves = the 4 (layer,tower) combos,
// running concurrently (R4 post-mortem: serializing them in one wave left
// MfmaUtil at 5% -- pure latency-bound chain). Cross-combo combine via 1KB
// LDS + one __syncthreads. s1/g1 LDS rows stay wave-private.
// Register-allocator history: __launch_bounds__(256) -> no spill; adding
// min-waves (256,2)/(256,3) forced 128/84 VGPR -> 184/547 MB scratch storms.
template <bool BT>
__global__ __launch_bounds__(256) void ckan_main(
    const int* __restrict__ items,
    const int* __restrict__ user_h, const int* __restrict__ user_r, const int* __restrict__ user_t,
    const int* __restrict__ item_h, const int* __restrict__ item_r, const int* __restrict__ item_t,
    const float* __restrict__ ent, const float* __restrict__ rel,
    const __bf16* __restrict__ wsb, const float* __restrict__ w3,
    float* __restrict__ out)
{
  __shared__ __align__(16) __bf16 s1buf[128][72];   // stride 144B: 16B-aligned rows
  __shared__ __align__(16) __bf16 g1buf[128][72];
  __shared__ float outbuf[4][64];                    // per-wave layer vectors

  const int tid  = threadIdx.x;
  const int w    = tid >> 6;     // wave = combo: l = w>>1, tower = w&1
  const int lane = tid & 63;
  const int b    = blockIdx.x;
  const int l    = w >> 1;
  const int tower = w & 1;
  const int r16  = lane & 15;
  const int g4   = lane >> 4;
  const int rb   = w * 32;       // wave-private LDS rows

  const __bf16* __restrict__ W1t = wsb;
  const __bf16* __restrict__ G1t = wsb + 8192;
  const __bf16* __restrict__ W2t = wsb + 16384;
  const __bf16* __restrict__ G2t = wsb + 20480;
  const __bf16* __restrict__ entb = wsb + ENTB_OFF;
  const __bf16* __restrict__ relb = wsb + RELB_OFF;

  const int* __restrict__ Hp = tower ? item_h : user_h;
  const int* __restrict__ Rp = tower ? item_r : user_r;
  const int* __restrict__ Tp = tower ? item_t : user_t;
  const int ibase = (l * NB + b) * NTOK;

  // per-lane w3 columns
  float w3c[4];
#pragma unroll
  for (int n = 0; n < 4; ++n) w3c[n] = w3[n * 16 + r16];

  // indices (broadcast cache lines)
  const int h0  = Hp[ibase + r16] * DIM;
  const int h1  = Hp[ibase + 16 + r16] * DIM;
  const int rr0 = Rp[ibase + r16] * DIM;
  const int rr1 = Rp[ibase + 16 + r16] * DIM;

  const f32x4 zero4 = {0.f, 0.f, 0.f, 0.f};

  // ---- GEMM1: x[32,128] @ {W1,G1}[128,64] ----
  f32x4 accS[2][4], accG[2][4];
#pragma unroll
  for (int m = 0; m < 2; ++m)
#pragma unroll
    for (int n = 0; n < 4; ++n) { accS[m][n] = zero4; accG[m][n] = zero4; }

#pragma unroll
  for (int kk = 0; kk < 4; ++kk) {
    bf16x8 afr[2];
#pragma unroll
    for (int m = 0; m < 2; ++m) {
      if (BT) {
        const __bf16* src = (kk < 2)
            ? entb + (m ? h1 : h0) + kk * 32 + g4 * 8
            : relb + (m ? rr1 : rr0) + (kk - 2) * 32 + g4 * 8;
        afr[m] = *(const bf16x8*)src;
      } else {
        const float* src = (kk < 2)
            ? ent + (m ? h1 : h0) + kk * 32 + g4 * 8
            : rel + (m ? rr1 : rr0) + (kk - 2) * 32 + g4 * 8;
        f32x4 lo = *(const f32x4*)(src);
        f32x4 hi = *(const f32x4*)(src + 4);
        bf16x8 a;
        a[0] = (__bf16)lo[0]; a[1] = (__bf16)lo[1]; a[2] = (__bf16)lo[2]; a[3] = (__bf16)lo[3];
        a[4] = (__bf16)hi[0]; a[5] = (__bf16)hi[1]; a[6] = (__bf16)hi[2]; a[7] = (__bf16)hi[3];
        afr[m] = a;
      }
    }
#pragma unroll
    for (int n = 0; n < 4; ++n) {
      bf16x8 bS = *(const bf16x8*)(W1t + (n * 16 + r16) * 128 + kk * 32 + g4 * 8);
      bf16x8 bG = *(const bf16x8*)(G1t + (n * 16 + r16) * 128 + kk * 32 + g4 * 8);
#pragma unroll
      for (int m = 0; m < 2; ++m) {
        accS[m][n] = mfma16(afr[m], bS, accS[m][n]);
        accG[m][n] = mfma16(afr[m], bG, accG[m][n]);
      }
    }
  }

  // ReLU + bf16 -> LDS (wave-private rows) for the GEMM2 transpose
#pragma unroll
  for (int m = 0; m < 2; ++m)
#pragma unroll
    for (int n = 0; n < 4; ++n)
#pragma unroll
      for (int i = 0; i < 4; ++i) {
        const int row = rb + m * 16 + g4 * 4 + i;
        const int col = n * 16 + r16;
        s1buf[row][col] = (__bf16)fmaxf(accS[m][n][i], 0.f);
        g1buf[row][col] = (__bf16)fmaxf(accG[m][n][i], 0.f);
      }

  // ---- GEMM2: s1@W2, g1@G2 (K=64) ----
  f32x4 acc2S[2][4], acc2G[2][4];
#pragma unroll
  for (int m = 0; m < 2; ++m)
#pragma unroll
    for (int n = 0; n < 4; ++n) { acc2S[m][n] = zero4; acc2G[m][n] = zero4; }
#pragma unroll
  for (int kk = 0; kk < 2; ++kk) {
    bf16x8 aS[2], aG[2];
#pragma unroll
    for (int m = 0; m < 2; ++m) {
      const int tok = rb + m * 16 + r16;
      aS[m] = *(const bf16x8*)&s1buf[tok][kk * 32 + g4 * 8];
      aG[m] = *(const bf16x8*)&g1buf[tok][kk * 32 + g4 * 8];
    }
#pragma unroll
    for (int n = 0; n < 4; ++n) {
      bf16x8 bS = *(const bf16x8*)(W2t + (n * 16 + r16) * 64 + kk * 32 + g4 * 8);
      bf16x8 bG = *(const bf16x8*)(G2t + (n * 16 + r16) * 64 + kk * 32 + g4 * 8);
#pragma unroll
      for (int m = 0; m < 2; ++m) {
        acc2S[m][n] = mfma16(aS[m], bS, acc2S[m][n]);
        acc2G[m][n] = mfma16(aG[m], bG, acc2G[m][n]);
      }
    }
  }

  // ---- s3/softmax entirely in registers ----
  float att[2][4];
  {
    float dotp[2][4];
#pragma unroll
    for (int m = 0; m < 2; ++m)
#pragma unroll
      for (int i = 0; i < 4; ++i) {
        float d = 0.f;
#pragma unroll
        for (int n = 0; n < 4; ++n)
          d += fmaxf(acc2S[m][n][i], 0.f) * w3c[n];
        dotp[m][i] = d;
      }
#pragma unroll
    for (int off = 1; off <= 8; off <<= 1)
#pragma unroll
      for (int m = 0; m < 2; ++m)
#pragma unroll
        for (int i = 0; i < 4; ++i)
          dotp[m][i] += __shfl_xor(dotp[m][i], off);
    float mx = -1.f;
#pragma unroll
    for (int m = 0; m < 2; ++m)
#pragma unroll
      for (int i = 0; i < 4; ++i) {
        dotp[m][i] = 1.f / (1.f + __expf(-dotp[m][i]));  // sc
        mx = fmaxf(mx, dotp[m][i]);
      }
    mx = fmaxf(mx, __shfl_xor(mx, 16));
    mx = fmaxf(mx, __shfl_xor(mx, 32));
    float sm = 0.f;
#pragma unroll
    for (int m = 0; m < 2; ++m)
#pragma unroll
      for (int i = 0; i < 4; ++i) {
        att[m][i] = __expf(dotp[m][i] - mx);
        sm += att[m][i];
      }
    sm += __shfl_xor(sm, 16);
    sm += __shfl_xor(sm, 32);
    const float inv = 1.f / sm;
#pragma unroll
    for (int m = 0; m < 2; ++m)
#pragma unroll
      for (int i = 0; i < 4; ++i) att[m][i] *= inv;
  }

  // ---- epilogue: layer_vec[d] = sum_t att[t] * 2*sigmoid(g2[t,d]) * t_e[t,d] ----
  float outn[4] = {0.f, 0.f, 0.f, 0.f};
#pragma unroll
  for (int m = 0; m < 2; ++m)
#pragma unroll
    for (int i = 0; i < 4; ++i) {
      const float at = att[m][i];
      const int to = Tp[ibase + m * 16 + g4 * 4 + i] * DIM;
#pragma unroll
      for (int n = 0; n < 4; ++n) {
        const float g2 = 2.f / (1.f + __expf(-acc2G[m][n][i]));
        const float te = BT ? (float)entb[to + n * 16 + r16]
                            : ent[to + n * 16 + r16];
        outn[n] += at * g2 * te;
      }
    }
#pragma unroll
  for (int n = 0; n < 4; ++n) {          // reduce over the 4 g4 groups
    outn[n] += __shfl_xor(outn[n], 16);
    outn[n] += __shfl_xor(outn[n], 32);
  }
  if (g4 == 0) {
#pragma unroll
    for (int n = 0; n < 4; ++n) outbuf[w][n * 16 + r16] = outn[n];
  }

  // ---- wave 0: origin vectors (overlaps other waves' tails) ----
  float uo = 0.f, io = 0.f;
  if (w == 0) {
    const int ib0 = b * NTOK;
#pragma unroll 8
    for (int t = 0; t < NTOK; ++t) {
      const int ho = user_h[ib0 + t] * DIM + lane;
      uo += BT ? (float)entb[ho] : ent[ho];
    }
    uo *= (1.f / 32.f);
    const int io_o = items[b] * DIM + lane;
    io = BT ? (float)entb[io_o] : ent[io_o];
  }

  __syncthreads();

  if (w == 0) {
    // lane = dim d: e_u . e_v = uo*io + sum_l u_l[d]*i_l[d]
    float part = uo * io
               + outbuf[0][lane] * outbuf[1][lane]
               + outbuf[2][lane] * outbuf[3][lane];
#pragma unroll
    for (int off = 32; off >= 1; off >>= 1) part += __shfl_xor(part, off);
    if (lane == 0) out[b] = 1.f / (1.f + __expf(-part));
  }
}

extern "C" void kernel_launch(void* const* d_in, const int* in_sizes, int n_in,
                              void* d_out, int out_size, void* d_ws, size_t ws_size,
                              hipStream_t stream) {
  const int*   items  = (const int*)d_in[1];
  const int*   user_h = (const int*)d_in[2];
  const int*   user_r = (const int*)d_in[3];
  const int*   user_t = (const int*)d_in[4];
  const int*   item_h = (const int*)d_in[5];
  const int*   item_r = (const int*)d_in[6];
  const int*   item_t = (const int*)d_in[7];
  const float* ent    = (const float*)d_in[8];
  const float* rel    = (const float*)d_in[9];
  const float* W1     = (const float*)d_in[10];
  const float* W2     = (const float*)d_in[11];
  const float* w3     = (const float*)d_in[12];
  const float* G1     = (const float*)d_in[13];
  const float* G2     = (const float*)d_in[14];
  __bf16* wsb = (__bf16*)d_ws;
  float* out = (float*)d_out;

  const bool bt = ws_size >= WS_NEED_BYTES;
  prep_w<<<dim3(56), dim3(256), 0, stream>>>(W1, G1, W2, G2, rel, wsb, bt ? 1 : 0);
  if (bt) {
    prep_ent<<<dim3(3125), dim3(256), 0, stream>>>(ent, wsb + ENTB_OFF);
    ckan_main<true><<<dim3(NB), dim3(256), 0, stream>>>(
        items, user_h, user_r, user_t, item_h, item_r, item_t,
        ent, rel, wsb, w3, out);
  } else {
    ckan_main<false><<<dim3(NB), dim3(256), 0, stream>>>(
        items, user_h, user_r, user_t, item_h, item_r, item_t,
        ent, rel, wsb, w3, out);
  }
}

// Round 6
// 166.169 us; speedup vs baseline: 1.0864x; 1.0368x over previous
//
#include <hip/hip_runtime.h>

#define DIM 64
#define NB 4096
#define NTOK 32
#define NL 2

typedef __attribute__((ext_vector_type(8))) __bf16 bf16x8;
typedef __attribute__((ext_vector_type(4))) float f32x4;

__device__ __forceinline__ f32x4 mfma16(bf16x8 a, bf16x8 b, f32x4 c) {
  return __builtin_amdgcn_mfma_f32_16x16x32_bf16(a, b, c, 0, 0, 0);
}

// ws layout (bf16 elems): [0,24576) weights-T, [24576, +6.4M) ent bf16, then rel.
#define ENTB_OFF 24576
#define RELB_OFF (24576 + 100000 * 64)
#define WS_NEED_BYTES ((size_t)(RELB_OFF + 2048) * 2)

// LDS XOR swizzle: keeps 8-element (16B) blocks contiguous, spreads rows
// across bank groups (>=2-way everywhere -> free per m136).
#define SWC(row, col) ((col) ^ (((row) & 7) << 3))

// Transpose weights to bf16 [col][k] + convert rel table.
__global__ void prep_w(const float* __restrict__ W1, const float* __restrict__ G1,
                       const float* __restrict__ W2, const float* __restrict__ G2,
                       const float* __restrict__ rel, __bf16* __restrict__ ws,
                       int do_rel) {
  int i = blockIdx.x * 256 + threadIdx.x;
  if (i < 8192) {
    int c = i >> 7, k = i & 127;
    ws[i]        = (__bf16)W1[k * 64 + c];
    ws[8192 + i] = (__bf16)G1[k * 64 + c];
  } else if (i < 12288) {
    int j = i - 8192;
    int c = j >> 6, k = j & 63;
    ws[16384 + j] = (__bf16)W2[k * 64 + c];
    ws[20480 + j] = (__bf16)G2[k * 64 + c];
  } else if (do_rel && i < 14336) {
    int j = i - 12288;
    ws[RELB_OFF + j] = (__bf16)rel[j];
  }
}

// Convert ent table f32 -> bf16. 8 elems/thread.
__global__ void prep_ent(const float* __restrict__ ent, __bf16* __restrict__ entb) {
  int t = blockIdx.x * 256 + threadIdx.x;
  const float* src = ent + t * 8;
  f32x4 lo = *(const f32x4*)src;
  f32x4 hi = *(const f32x4*)(src + 4);
  bf16x8 v;
  v[0] = (__bf16)lo[0]; v[1] = (__bf16)lo[1]; v[2] = (__bf16)lo[2]; v[3] = (__bf16)lo[3];
  v[4] = (__bf16)hi[0]; v[5] = (__bf16)hi[1]; v[6] = (__bf16)hi[2]; v[7] = (__bf16)hi[3];
  *(bf16x8*)(entb + t * 8) = v;
}

// Block = one batch element; 4 waves = the 4 (layer,tower) combos.
// R6: fragment-style epilogue (p via LDS transpose + 16B t_e loads), uo
// folded into wave0's GEMM1 A-fragments, no-max softmax, swizzled no-pad LDS.
// Register-allocator history: plain __launch_bounds__(256) -> no spill;
// any min-waves arg forced VGPR below the live acc set -> scratch storms.
__global__ __launch_bounds__(256) void ckan_fast(
    const int* __restrict__ items, const int* __restrict__ user_h,
    const int* __restrict__ user_r, const int* __restrict__ user_t,
    const int* __restrict__ item_h, const int* __restrict__ item_r,
    const int* __restrict__ item_t,
    const __bf16* __restrict__ wsb, const float* __restrict__ w3,
    float* __restrict__ out)
{
  __shared__ __align__(16) __bf16 s1buf[128][64];   // 16 KB (swizzled cols)
  __shared__ __align__(16) __bf16 g1buf[128][64];   // 16 KB
  __shared__ float outbuf[4][64];                    // 1 KB

  const int tid  = threadIdx.x;
  const int w    = tid >> 6;      // combo: l = w>>1, tower = w&1
  const int lane = tid & 63;
  const int b    = blockIdx.x;
  const int l    = w >> 1;
  const int tower = w & 1;
  const int r16  = lane & 15;
  const int g4   = lane >> 4;
  const int rb   = w * 32;        // wave-private LDS rows

  const __bf16* __restrict__ W1t = wsb;
  const __bf16* __restrict__ G1t = wsb + 8192;
  const __bf16* __restrict__ W2t = wsb + 16384;
  const __bf16* __restrict__ G2t = wsb + 20480;
  const __bf16* __restrict__ entb = wsb + ENTB_OFF;
  const __bf16* __restrict__ relb = wsb + RELB_OFF;

  const int* __restrict__ Hp = tower ? item_h : user_h;
  const int* __restrict__ Rp = tower ? item_r : user_r;
  const int* __restrict__ Tp = tower ? item_t : user_t;
  const int ibase = (l * NB + b) * NTOK;

  float w3c[4];
#pragma unroll
  for (int n = 0; n < 4; ++n) w3c[n] = w3[n * 16 + r16];

  const int h0  = Hp[ibase + r16] * DIM;
  const int h1  = Hp[ibase + 16 + r16] * DIM;
  const int rr0 = Rp[ibase + r16] * DIM;
  const int rr1 = Rp[ibase + 16 + r16] * DIM;

  const f32x4 zero4 = {0.f, 0.f, 0.f, 0.f};

  // wave0 accumulates the user-origin mean from its own A-fragments (free)
  float uo8[2][8];
#pragma unroll
  for (int k2 = 0; k2 < 2; ++k2)
#pragma unroll
    for (int j = 0; j < 8; ++j) uo8[k2][j] = 0.f;

  // ---- GEMM1: x[32,128] @ {W1,G1}[128,64] ----
  f32x4 accS[2][4], accG[2][4];
#pragma unroll
  for (int m = 0; m < 2; ++m)
#pragma unroll
    for (int n = 0; n < 4; ++n) { accS[m][n] = zero4; accG[m][n] = zero4; }

#pragma unroll
  for (int kk = 0; kk < 4; ++kk) {
    bf16x8 afr[2];
#pragma unroll
    for (int m = 0; m < 2; ++m) {
      const __bf16* src = (kk < 2)
          ? entb + (m ? h1 : h0) + kk * 32 + g4 * 8
          : relb + (m ? rr1 : rr0) + (kk - 2) * 32 + g4 * 8;
      afr[m] = *(const bf16x8*)src;
    }
    if (w == 0 && kk < 2) {   // wave-uniform branch
#pragma unroll
      for (int m = 0; m < 2; ++m)
#pragma unroll
        for (int j = 0; j < 8; ++j) uo8[kk][j] += (float)afr[m][j];
    }
#pragma unroll
    for (int n = 0; n < 4; ++n) {
      bf16x8 bS = *(const bf16x8*)(W1t + (n * 16 + r16) * 128 + kk * 32 + g4 * 8);
      bf16x8 bG = *(const bf16x8*)(G1t + (n * 16 + r16) * 128 + kk * 32 + g4 * 8);
#pragma unroll
      for (int m = 0; m < 2; ++m) {
        accS[m][n] = mfma16(afr[m], bS, accS[m][n]);
        accG[m][n] = mfma16(afr[m], bG, accG[m][n]);
      }
    }
  }

  // ReLU + bf16 -> LDS (wave-private, swizzled)
#pragma unroll
  for (int m = 0; m < 2; ++m)
#pragma unroll
    for (int n = 0; n < 4; ++n)
#pragma unroll
      for (int i = 0; i < 4; ++i) {
        const int row = rb + m * 16 + g4 * 4 + i;
        const int col = n * 16 + r16;
        s1buf[row][SWC(row, col)] = (__bf16)fmaxf(accS[m][n][i], 0.f);
        g1buf[row][SWC(row, col)] = (__bf16)fmaxf(accG[m][n][i], 0.f);
      }

  // ---- GEMM2: s1@W2, g1@G2 (K=64) ----
  f32x4 acc2S[2][4], acc2G[2][4];
#pragma unroll
  for (int m = 0; m < 2; ++m)
#pragma unroll
    for (int n = 0; n < 4; ++n) { acc2S[m][n] = zero4; acc2G[m][n] = zero4; }
#pragma unroll
  for (int kk = 0; kk < 2; ++kk) {
    bf16x8 aS[2], aG[2];
#pragma unroll
    for (int m = 0; m < 2; ++m) {
      const int tok = rb + m * 16 + r16;
      const int cb  = SWC(tok, kk * 32 + g4 * 8);
      aS[m] = *(const bf16x8*)&s1buf[tok][cb];
      aG[m] = *(const bf16x8*)&g1buf[tok][cb];
    }
#pragma unroll
    for (int n = 0; n < 4; ++n) {
      bf16x8 bS = *(const bf16x8*)(W2t + (n * 16 + r16) * 64 + kk * 32 + g4 * 8);
      bf16x8 bG = *(const bf16x8*)(G2t + (n * 16 + r16) * 64 + kk * 32 + g4 * 8);
#pragma unroll
      for (int m = 0; m < 2; ++m) {
        acc2S[m][n] = mfma16(aS[m], bS, acc2S[m][n]);
        acc2G[m][n] = mfma16(aG[m], bG, acc2G[m][n]);
      }
    }
  }

  // ---- s3 + softmax (no max pass: scores are sigmoids in (0,1)) ----
  float att[2][4];
  {
    float dotp[2][4];
#pragma unroll
    for (int m = 0; m < 2; ++m)
#pragma unroll
      for (int i = 0; i < 4; ++i) {
        float d = 0.f;
#pragma unroll
        for (int n = 0; n < 4; ++n)
          d += fmaxf(acc2S[m][n][i], 0.f) * w3c[n];
        dotp[m][i] = d;
      }
#pragma unroll
    for (int off = 1; off <= 8; off <<= 1)
#pragma unroll
      for (int m = 0; m < 2; ++m)
#pragma unroll
        for (int i = 0; i < 4; ++i)
          dotp[m][i] += __shfl_xor(dotp[m][i], off);
    float den = 0.f;
#pragma unroll
    for (int m = 0; m < 2; ++m)
#pragma unroll
      for (int i = 0; i < 4; ++i) {
        const float sc = 1.f / (1.f + __expf(-dotp[m][i]));
        att[m][i] = __expf(sc);
        den += att[m][i];
      }
    den += __shfl_xor(den, 16);
    den += __shfl_xor(den, 32);
    const float inv = 1.f / den;
#pragma unroll
    for (int m = 0; m < 2; ++m)
#pragma unroll
      for (int i = 0; i < 4; ++i) att[m][i] *= inv;
  }

  // ---- epilogue: p = att * 2*sigmoid(g2) -> LDS [t][d]; fragment t_e ----
#pragma unroll
  for (int m = 0; m < 2; ++m)
#pragma unroll
    for (int n = 0; n < 4; ++n)
#pragma unroll
      for (int i = 0; i < 4; ++i) {
        const int row = rb + m * 16 + g4 * 4 + i;
        const int col = n * 16 + r16;
        const float g2v = 2.f / (1.f + __expf(-acc2G[m][n][i]));
        s1buf[row][SWC(row, col)] = (__bf16)(att[m][i] * g2v);
      }

  int tof2[2];
#pragma unroll
  for (int m2 = 0; m2 < 2; ++m2)
    tof2[m2] = Tp[ibase + m2 * 16 + r16] * DIM;

  float dsum[2][8];
#pragma unroll
  for (int h = 0; h < 2; ++h)
#pragma unroll
    for (int j = 0; j < 8; ++j) dsum[h][j] = 0.f;

#pragma unroll
  for (int m2 = 0; m2 < 2; ++m2) {
    const int prow = rb + m2 * 16 + r16;
#pragma unroll
    for (int h = 0; h < 2; ++h) {
      bf16x8 pf = *(const bf16x8*)&s1buf[prow][SWC(prow, h * 32 + g4 * 8)];
      bf16x8 tf = *(const bf16x8*)(entb + tof2[m2] + h * 32 + g4 * 8);
#pragma unroll
      for (int j = 0; j < 8; ++j)
        dsum[h][j] += (float)pf[j] * (float)tf[j];
    }
  }
  // reduce over the 16 tokens held across the r16 lanes
#pragma unroll
  for (int off = 1; off <= 8; off <<= 1)
#pragma unroll
    for (int h = 0; h < 2; ++h)
#pragma unroll
      for (int j = 0; j < 8; ++j)
        dsum[h][j] += __shfl_xor(dsum[h][j], off);
  if (r16 == 0) {
#pragma unroll
    for (int h = 0; h < 2; ++h)
#pragma unroll
      for (int j = 0; j < 8; ++j)
        outbuf[w][h * 32 + g4 * 8 + j] = dsum[h][j];
  }

  // ---- wave0: finish origin dot (uo from GEMM1 fragments, io fragments) ----
  float partU = 0.f;
  if (w == 0) {
#pragma unroll
    for (int off = 1; off <= 8; off <<= 1)
#pragma unroll
      for (int k2 = 0; k2 < 2; ++k2)
#pragma unroll
        for (int j = 0; j < 8; ++j)
          uo8[k2][j] += __shfl_xor(uo8[k2][j], off);
    const __bf16* iorow = entb + items[b] * DIM;
#pragma unroll
    for (int h = 0; h < 2; ++h) {
      bf16x8 iof = *(const bf16x8*)(iorow + h * 32 + g4 * 8);
#pragma unroll
      for (int j = 0; j < 8; ++j)
        partU += uo8[h][j] * (1.f / 32.f) * (float)iof[j];
    }
    if (r16 != 0) partU = 0.f;
  }

  __syncthreads();

  if (w == 0) {
    float part = partU
               + outbuf[0][lane] * outbuf[1][lane]
               + outbuf[2][lane] * outbuf[3][lane];
#pragma unroll
    for (int off = 32; off >= 1; off >>= 1) part += __shfl_xor(part, off);
    if (lane == 0) out[b] = 1.f / (1.f + __expf(-part));
  }
}

// -------- fallback (ws too small for bf16 table): R5 kernel, f32 path --------
__global__ __launch_bounds__(256) void ckan_ref(
    const int* __restrict__ items, const int* __restrict__ user_h,
    const int* __restrict__ user_r, const int* __restrict__ user_t,
    const int* __restrict__ item_h, const int* __restrict__ item_r,
    const int* __restrict__ item_t,
    const float* __restrict__ ent, const float* __restrict__ rel,
    const __bf16* __restrict__ wsb, const float* __restrict__ w3,
    float* __restrict__ out)
{
  __shared__ __align__(16) __bf16 s1buf[128][72];
  __shared__ __align__(16) __bf16 g1buf[128][72];
  __shared__ float outbuf[4][64];

  const int tid  = threadIdx.x;
  const int w    = tid >> 6;
  const int lane = tid & 63;
  const int b    = blockIdx.x;
  const int l    = w >> 1;
  const int tower = w & 1;
  const int r16  = lane & 15;
  const int g4   = lane >> 4;
  const int rb   = w * 32;

  const __bf16* __restrict__ W1t = wsb;
  const __bf16* __restrict__ G1t = wsb + 8192;
  const __bf16* __restrict__ W2t = wsb + 16384;
  const __bf16* __restrict__ G2t = wsb + 20480;

  const int* __restrict__ Hp = tower ? item_h : user_h;
  const int* __restrict__ Rp = tower ? item_r : user_r;
  const int* __restrict__ Tp = tower ? item_t : user_t;
  const int ibase = (l * NB + b) * NTOK;

  float w3c[4];
#pragma unroll
  for (int n = 0; n < 4; ++n) w3c[n] = w3[n * 16 + r16];

  const int h0  = Hp[ibase + r16] * DIM;
  const int h1  = Hp[ibase + 16 + r16] * DIM;
  const int rr0 = Rp[ibase + r16] * DIM;
  const int rr1 = Rp[ibase + 16 + r16] * DIM;

  const f32x4 zero4 = {0.f, 0.f, 0.f, 0.f};

  f32x4 accS[2][4], accG[2][4];
#pragma unroll
  for (int m = 0; m < 2; ++m)
#pragma unroll
    for (int n = 0; n < 4; ++n) { accS[m][n] = zero4; accG[m][n] = zero4; }

#pragma unroll
  for (int kk = 0; kk < 4; ++kk) {
    bf16x8 afr[2];
#pragma unroll
    for (int m = 0; m < 2; ++m) {
      const float* src = (kk < 2)
          ? ent + (m ? h1 : h0) + kk * 32 + g4 * 8
          : rel + (m ? rr1 : rr0) + (kk - 2) * 32 + g4 * 8;
      f32x4 lo = *(const f32x4*)(src);
      f32x4 hi = *(const f32x4*)(src + 4);
      bf16x8 a;
      a[0] = (__bf16)lo[0]; a[1] = (__bf16)lo[1]; a[2] = (__bf16)lo[2]; a[3] = (__bf16)lo[3];
      a[4] = (__bf16)hi[0]; a[5] = (__bf16)hi[1]; a[6] = (__bf16)hi[2]; a[7] = (__bf16)hi[3];
      afr[m] = a;
    }
#pragma unroll
    for (int n = 0; n < 4; ++n) {
      bf16x8 bS = *(const bf16x8*)(W1t + (n * 16 + r16) * 128 + kk * 32 + g4 * 8);
      bf16x8 bG = *(const bf16x8*)(G1t + (n * 16 + r16) * 128 + kk * 32 + g4 * 8);
#pragma unroll
      for (int m = 0; m < 2; ++m) {
        accS[m][n] = mfma16(afr[m], bS, accS[m][n]);
        accG[m][n] = mfma16(afr[m], bG, accG[m][n]);
      }
    }
  }

#pragma unroll
  for (int m = 0; m < 2; ++m)
#pragma unroll
    for (int n = 0; n < 4; ++n)
#pragma unroll
      for (int i = 0; i < 4; ++i) {
        const int row = rb + m * 16 + g4 * 4 + i;
        const int col = n * 16 + r16;
        s1buf[row][col] = (__bf16)fmaxf(accS[m][n][i], 0.f);
        g1buf[row][col] = (__bf16)fmaxf(accG[m][n][i], 0.f);
      }

  f32x4 acc2S[2][4], acc2G[2][4];
#pragma unroll
  for (int m = 0; m < 2; ++m)
#pragma unroll
    for (int n = 0; n < 4; ++n) { acc2S[m][n] = zero4; acc2G[m][n] = zero4; }
#pragma unroll
  for (int kk = 0; kk < 2; ++kk) {
    bf16x8 aS[2], aG[2];
#pragma unroll
    for (int m = 0; m < 2; ++m) {
      const int tok = rb + m * 16 + r16;
      aS[m] = *(const bf16x8*)&s1buf[tok][kk * 32 + g4 * 8];
      aG[m] = *(const bf16x8*)&g1buf[tok][kk * 32 + g4 * 8];
    }
#pragma unroll
    for (int n = 0; n < 4; ++n) {
      bf16x8 bS = *(const bf16x8*)(W2t + (n * 16 + r16) * 64 + kk * 32 + g4 * 8);
      bf16x8 bG = *(const bf16x8*)(G2t + (n * 16 + r16) * 64 + kk * 32 + g4 * 8);
#pragma unroll
      for (int m = 0; m < 2; ++m) {
        acc2S[m][n] = mfma16(aS[m], bS, acc2S[m][n]);
        acc2G[m][n] = mfma16(aG[m], bG, acc2G[m][n]);
      }
    }
  }

  float att[2][4];
  {
    float dotp[2][4];
#pragma unroll
    for (int m = 0; m < 2; ++m)
#pragma unroll
      for (int i = 0; i < 4; ++i) {
        float d = 0.f;
#pragma unroll
        for (int n = 0; n < 4; ++n)
          d += fmaxf(acc2S[m][n][i], 0.f) * w3c[n];
        dotp[m][i] = d;
      }
#pragma unroll
    for (int off = 1; off <= 8; off <<= 1)
#pragma unroll
      for (int m = 0; m < 2; ++m)
#pragma unroll
        for (int i = 0; i < 4; ++i)
          dotp[m][i] += __shfl_xor(dotp[m][i], off);
    float den = 0.f;
#pragma unroll
    for (int m = 0; m < 2; ++m)
#pragma unroll
      for (int i = 0; i < 4; ++i) {
        const float sc = 1.f / (1.f + __expf(-dotp[m][i]));
        att[m][i] = __expf(sc);
        den += att[m][i];
      }
    den += __shfl_xor(den, 16);
    den += __shfl_xor(den, 32);
    const float inv = 1.f / den;
#pragma unroll
    for (int m = 0; m < 2; ++m)
#pragma unroll
      for (int i = 0; i < 4; ++i) att[m][i] *= inv;
  }

  float outn[4] = {0.f, 0.f, 0.f, 0.f};
#pragma unroll
  for (int m = 0; m < 2; ++m)
#pragma unroll
    for (int i = 0; i < 4; ++i) {
      const float at = att[m][i];
      const int to = Tp[ibase + m * 16 + g4 * 4 + i] * DIM;
#pragma unroll
      for (int n = 0; n < 4; ++n) {
        const float g2 = 2.f / (1.f + __expf(-acc2G[m][n][i]));
        outn[n] += at * g2 * ent[to + n * 16 + r16];
      }
    }
#pragma unroll
  for (int n = 0; n < 4; ++n) {
    outn[n] += __shfl_xor(outn[n], 16);
    outn[n] += __shfl_xor(outn[n], 32);
  }
  if (g4 == 0) {
#pragma unroll
    for (int n = 0; n < 4; ++n) outbuf[w][n * 16 + r16] = outn[n];
  }

  float uo = 0.f, io = 0.f;
  if (w == 0) {
    const int ib0 = b * NTOK;
#pragma unroll 8
    for (int t = 0; t < NTOK; ++t) uo += ent[user_h[ib0 + t] * DIM + lane];
    uo *= (1.f / 32.f);
    io = ent[items[b] * DIM + lane];
  }

  __syncthreads();

  if (w == 0) {
    float part = uo * io
               + outbuf[0][lane] * outbuf[1][lane]
               + outbuf[2][lane] * outbuf[3][lane];
#pragma unroll
    for (int off = 32; off >= 1; off >>= 1) part += __shfl_xor(part, off);
    if (lane == 0) out[b] = 1.f / (1.f + __expf(-part));
  }
}

extern "C" void kernel_launch(void* const* d_in, const int* in_sizes, int n_in,
                              void* d_out, int out_size, void* d_ws, size_t ws_size,
                              hipStream_t stream) {
  const int*   items  = (const int*)d_in[1];
  const int*   user_h = (const int*)d_in[2];
  const int*   user_r = (const int*)d_in[3];
  const int*   user_t = (const int*)d_in[4];
  const int*   item_h = (const int*)d_in[5];
  const int*   item_r = (const int*)d_in[6];
  const int*   item_t = (const int*)d_in[7];
  const float* ent    = (const float*)d_in[8];
  const float* rel    = (const float*)d_in[9];
  const float* W1     = (const float*)d_in[10];
  const float* W2     = (const float*)d_in[11];
  const float* w3     = (const float*)d_in[12];
  const float* G1     = (const float*)d_in[13];
  const float* G2     = (const float*)d_in[14];
  __bf16* wsb = (__bf16*)d_ws;
  float* out = (float*)d_out;

  const bool bt = ws_size >= WS_NEED_BYTES;
  prep_w<<<dim3(56), dim3(256), 0, stream>>>(W1, G1, W2, G2, rel, wsb, bt ? 1 : 0);
  if (bt) {
    prep_ent<<<dim3(3125), dim3(256), 0, stream>>>(ent, wsb + ENTB_OFF);
    ckan_fast<<<dim3(NB), dim3(256), 0, stream>>>(
        items, user_h, user_r, user_t, item_h, item_r, item_t,
        wsb, w3, out);
  } else {
    ckan_ref<<<dim3(NB), dim3(256), 0, stream>>>(
        items, user_h, user_r, user_t, item_h, item_r, item_t,
        ent, rel, wsb, w3, out);
  }
}

// Round 7
// 163.513 us; speedup vs baseline: 1.1040x; 1.0162x over previous
//
#include <hip/hip_runtime.h>

#define DIM 64
#define NB 4096
#define NTOK 32
#define NL 2

typedef __attribute__((ext_vector_type(8))) __bf16 bf16x8;
typedef __attribute__((ext_vector_type(4))) float f32x4;

__device__ __forceinline__ f32x4 mfma16(bf16x8 a, bf16x8 b, f32x4 c) {
  return __builtin_amdgcn_mfma_f32_16x16x32_bf16(a, b, c, 0, 0, 0);
}

// LDS XOR swizzle: keeps 8-element (16B) blocks contiguous, spreads rows
// across bank groups (bank conflicts measured 0 with this in R6).
#define SWC(row, col) ((col) ^ (((row) & 7) << 3))

// Transpose weights to bf16 [col][k] in ws:
// W1t[64][128], G1t[64][128], W2t[64][64], G2t[64][64]  (48 KB total)
__global__ void prep_w(const float* __restrict__ W1, const float* __restrict__ G1,
                       const float* __restrict__ W2, const float* __restrict__ G2,
                       __bf16* __restrict__ ws) {
  int i = blockIdx.x * 256 + threadIdx.x;
  if (i < 8192) {
    int c = i >> 7, k = i & 127;
    ws[i]        = (__bf16)W1[k * 64 + c];
    ws[8192 + i] = (__bf16)G1[k * 64 + c];
  } else if (i < 12288) {
    int j = i - 8192;
    int c = j >> 6, k = j & 63;
    ws[16384 + j] = (__bf16)W2[k * 64 + c];
    ws[20480 + j] = (__bf16)G2[k * 64 + c];
  }
}

// Block = one batch element; 4 waves = the 4 (layer,tower) combos.
// R7: f32 gathers + in-register cvt (prep_ent dropped -- it cost ~20us and
// bought nothing: tables are L3-resident either way). Single 16KB LDS buffer
// per block (combined GEMM1, sequential S/G GEMM2, buffer reused s1->g1->p)
// -> 9 blocks/CU capacity (was 4). Fragment epilogue, register softmax.
// Register-allocator history: plain __launch_bounds__(256) -> no spill; any
// min-waves arg forced VGPR below the live acc set -> 184-547 MB scratch
// storms (R2/R3). Leave it off.
__global__ __launch_bounds__(256) void ckan_fast(
    const int* __restrict__ items, const int* __restrict__ user_h,
    const int* __restrict__ user_r, const int* __restrict__ user_t,
    const int* __restrict__ item_h, const int* __restrict__ item_r,
    const int* __restrict__ item_t,
    const float* __restrict__ ent, const float* __restrict__ rel,
    const __bf16* __restrict__ wsb, const float* __restrict__ w3,
    float* __restrict__ out)
{
  __shared__ __align__(16) __bf16 buf[128][64];   // 16 KB, wave-private rows
  __shared__ float outbuf[4][64];                  // 1 KB

  const int tid  = threadIdx.x;
  const int w    = tid >> 6;      // combo: l = w>>1, tower = w&1
  const int lane = tid & 63;
  const int b    = blockIdx.x;
  const int l    = w >> 1;
  const int tower = w & 1;
  const int r16  = lane & 15;
  const int g4   = lane >> 4;
  const int rb   = w * 32;        // wave-private LDS rows

  const __bf16* __restrict__ W1t = wsb;
  const __bf16* __restrict__ G1t = wsb + 8192;
  const __bf16* __restrict__ W2t = wsb + 16384;
  const __bf16* __restrict__ G2t = wsb + 20480;

  const int* __restrict__ Hp = tower ? item_h : user_h;
  const int* __restrict__ Rp = tower ? item_r : user_r;
  const int* __restrict__ Tp = tower ? item_t : user_t;
  const int ibase = (l * NB + b) * NTOK;

  float w3c[4];
#pragma unroll
  for (int n = 0; n < 4; ++n) w3c[n] = w3[n * 16 + r16];

  const int h0  = Hp[ibase + r16] * DIM;
  const int h1  = Hp[ibase + 16 + r16] * DIM;
  const int rr0 = Rp[ibase + r16] * DIM;
  const int rr1 = Rp[ibase + 16 + r16] * DIM;

  const f32x4 zero4 = {0.f, 0.f, 0.f, 0.f};

  // wave0 accumulates the user-origin mean from its own x-fragments (free)
  float uo8[2][8];
#pragma unroll
  for (int k2 = 0; k2 < 2; ++k2)
#pragma unroll
    for (int j = 0; j < 8; ++j) uo8[k2][j] = 0.f;

  // ---- load all A-fragments (f32 gathers, cvt in-register) ----
  bf16x8 afr[4][2];
#pragma unroll
  for (int kk = 0; kk < 4; ++kk)
#pragma unroll
    for (int m = 0; m < 2; ++m) {
      const float* src = (kk < 2)
          ? ent + (m ? h1 : h0) + kk * 32 + g4 * 8
          : rel + (m ? rr1 : rr0) + (kk - 2) * 32 + g4 * 8;
      f32x4 lo = *(const f32x4*)(src);
      f32x4 hi = *(const f32x4*)(src + 4);
      if (w == 0 && kk < 2) {      // wave-uniform branch
#pragma unroll
        for (int j = 0; j < 4; ++j) {
          uo8[kk][j]     += lo[j];
          uo8[kk][4 + j] += hi[j];
        }
      }
      bf16x8 a;
      a[0] = (__bf16)lo[0]; a[1] = (__bf16)lo[1]; a[2] = (__bf16)lo[2]; a[3] = (__bf16)lo[3];
      a[4] = (__bf16)hi[0]; a[5] = (__bf16)hi[1]; a[6] = (__bf16)hi[2]; a[7] = (__bf16)hi[3];
      afr[kk][m] = a;
    }

  // ---- GEMM1 (combined S+G): x[32,128] @ {W1,G1}[128,64] ----
  f32x4 accS[2][4], accG[2][4];
#pragma unroll
  for (int m = 0; m < 2; ++m)
#pragma unroll
    for (int n = 0; n < 4; ++n) { accS[m][n] = zero4; accG[m][n] = zero4; }
#pragma unroll
  for (int kk = 0; kk < 4; ++kk)
#pragma unroll
    for (int n = 0; n < 4; ++n) {
      bf16x8 bS = *(const bf16x8*)(W1t + (n * 16 + r16) * 128 + kk * 32 + g4 * 8);
      bf16x8 bG = *(const bf16x8*)(G1t + (n * 16 + r16) * 128 + kk * 32 + g4 * 8);
#pragma unroll
      for (int m = 0; m < 2; ++m) {
        accS[m][n] = mfma16(afr[kk][m], bS, accS[m][n]);
        accG[m][n] = mfma16(afr[kk][m], bG, accG[m][n]);
      }
    }

  // ---- S path: relu(s1) -> buf -> GEMM2-S -> att ----
#pragma unroll
  for (int m = 0; m < 2; ++m)
#pragma unroll
    for (int n = 0; n < 4; ++n)
#pragma unroll
      for (int i = 0; i < 4; ++i) {
        const int row = rb + m * 16 + g4 * 4 + i;
        const int col = n * 16 + r16;
        buf[row][SWC(row, col)] = (__bf16)fmaxf(accS[m][n][i], 0.f);
      }

  f32x4 acc2S[2][4];
#pragma unroll
  for (int m = 0; m < 2; ++m)
#pragma unroll
    for (int n = 0; n < 4; ++n) acc2S[m][n] = zero4;
#pragma unroll
  for (int kk = 0; kk < 2; ++kk) {
    bf16x8 aS[2];
#pragma unroll
    for (int m = 0; m < 2; ++m) {
      const int tok = rb + m * 16 + r16;
      aS[m] = *(const bf16x8*)&buf[tok][SWC(tok, kk * 32 + g4 * 8)];
    }
#pragma unroll
    for (int n = 0; n < 4; ++n) {
      bf16x8 bS = *(const bf16x8*)(W2t + (n * 16 + r16) * 64 + kk * 32 + g4 * 8);
#pragma unroll
      for (int m = 0; m < 2; ++m) acc2S[m][n] = mfma16(aS[m], bS, acc2S[m][n]);
    }
  }

  // s3 + softmax (no max pass: scores are sigmoids in (0,1))
  float att[2][4];
  {
    float dotp[2][4];
#pragma unroll
    for (int m = 0; m < 2; ++m)
#pragma unroll
      for (int i = 0; i < 4; ++i) {
        float d = 0.f;
#pragma unroll
        for (int n = 0; n < 4; ++n)
          d += fmaxf(acc2S[m][n][i], 0.f) * w3c[n];
        dotp[m][i] = d;
      }
#pragma unroll
    for (int off = 1; off <= 8; off <<= 1)
#pragma unroll
      for (int m = 0; m < 2; ++m)
#pragma unroll
        for (int i = 0; i < 4; ++i)
          dotp[m][i] += __shfl_xor(dotp[m][i], off);
    float den = 0.f;
#pragma unroll
    for (int m = 0; m < 2; ++m)
#pragma unroll
      for (int i = 0; i < 4; ++i) {
        const float sc = 1.f / (1.f + __expf(-dotp[m][i]));
        att[m][i] = __expf(sc);
        den += att[m][i];
      }
    den += __shfl_xor(den, 16);
    den += __shfl_xor(den, 32);
    const float inv = 1.f / den;
#pragma unroll
    for (int m = 0; m < 2; ++m)
#pragma unroll
      for (int i = 0; i < 4; ++i) att[m][i] *= inv;
  }

  // ---- G path: relu(g1) -> buf (reuse) -> GEMM2-G ----
#pragma unroll
  for (int m = 0; m < 2; ++m)
#pragma unroll
    for (int n = 0; n < 4; ++n)
#pragma unroll
      for (int i = 0; i < 4; ++i) {
        const int row = rb + m * 16 + g4 * 4 + i;
        const int col = n * 16 + r16;
        buf[row][SWC(row, col)] = (__bf16)fmaxf(accG[m][n][i], 0.f);
      }

  f32x4 acc2G[2][4];
#pragma unroll
  for (int m = 0; m < 2; ++m)
#pragma unroll
    for (int n = 0; n < 4; ++n) acc2G[m][n] = zero4;
#pragma unroll
  for (int kk = 0; kk < 2; ++kk) {
    bf16x8 aG[2];
#pragma unroll
    for (int m = 0; m < 2; ++m) {
      const int tok = rb + m * 16 + r16;
      aG[m] = *(const bf16x8*)&buf[tok][SWC(tok, kk * 32 + g4 * 8)];
    }
#pragma unroll
    for (int n = 0; n < 4; ++n) {
      bf16x8 bG = *(const bf16x8*)(G2t + (n * 16 + r16) * 64 + kk * 32 + g4 * 8);
#pragma unroll
      for (int m = 0; m < 2; ++m) acc2G[m][n] = mfma16(aG[m], bG, acc2G[m][n]);
    }
  }

  // ---- epilogue: p = att * 2*sigmoid(g2) -> buf [t][d]; f32 t_e fragments ----
#pragma unroll
  for (int m = 0; m < 2; ++m)
#pragma unroll
    for (int n = 0; n < 4; ++n)
#pragma unroll
      for (int i = 0; i < 4; ++i) {
        const int row = rb + m * 16 + g4 * 4 + i;
        const int col = n * 16 + r16;
        const float g2v = 2.f / (1.f + __expf(-acc2G[m][n][i]));
        buf[row][SWC(row, col)] = (__bf16)(att[m][i] * g2v);
      }

  int tof2[2];
#pragma unroll
  for (int m2 = 0; m2 < 2; ++m2)
    tof2[m2] = Tp[ibase + m2 * 16 + r16] * DIM;

  float dsum[2][8];
#pragma unroll
  for (int h = 0; h < 2; ++h)
#pragma unroll
    for (int j = 0; j < 8; ++j) dsum[h][j] = 0.f;

#pragma unroll
  for (int m2 = 0; m2 < 2; ++m2) {
    const int prow = rb + m2 * 16 + r16;
#pragma unroll
    for (int h = 0; h < 2; ++h) {
      bf16x8 pf = *(const bf16x8*)&buf[prow][SWC(prow, h * 32 + g4 * 8)];
      const float* tsrc = ent + tof2[m2] + h * 32 + g4 * 8;
      f32x4 tlo = *(const f32x4*)(tsrc);
      f32x4 thi = *(const f32x4*)(tsrc + 4);
#pragma unroll
      for (int j = 0; j < 4; ++j) {
        dsum[h][j]     += (float)pf[j]     * tlo[j];
        dsum[h][4 + j] += (float)pf[4 + j] * thi[j];
      }
    }
  }
  // reduce over the 16 tokens held across the r16 lanes
#pragma unroll
  for (int off = 1; off <= 8; off <<= 1)
#pragma unroll
    for (int h = 0; h < 2; ++h)
#pragma unroll
      for (int j = 0; j < 8; ++j)
        dsum[h][j] += __shfl_xor(dsum[h][j], off);
  if (r16 == 0) {
#pragma unroll
    for (int h = 0; h < 2; ++h)
#pragma unroll
      for (int j = 0; j < 8; ++j)
        outbuf[w][h * 32 + g4 * 8 + j] = dsum[h][j];
  }

  // ---- wave0: finish origin dot (uo from x-fragments, io f32 fragments) ----
  float partU = 0.f;
  if (w == 0) {
#pragma unroll
    for (int off = 1; off <= 8; off <<= 1)
#pragma unroll
      for (int k2 = 0; k2 < 2; ++k2)
#pragma unroll
        for (int j = 0; j < 8; ++j)
          uo8[k2][j] += __shfl_xor(uo8[k2][j], off);
    const float* iorow = ent + items[b] * DIM;
#pragma unroll
    for (int h = 0; h < 2; ++h) {
      const float* isrc = iorow + h * 32 + g4 * 8;
      f32x4 ilo = *(const f32x4*)(isrc);
      f32x4 ihi = *(const f32x4*)(isrc + 4);
#pragma unroll
      for (int j = 0; j < 4; ++j) {
        partU += uo8[h][j]     * (1.f / 32.f) * ilo[j];
        partU += uo8[h][4 + j] * (1.f / 32.f) * ihi[j];
      }
    }
    if (r16 != 0) partU = 0.f;
  }

  __syncthreads();

  if (w == 0) {
    float part = partU
               + outbuf[0][lane] * outbuf[1][lane]
               + outbuf[2][lane] * outbuf[3][lane];
#pragma unroll
    for (int off = 32; off >= 1; off >>= 1) part += __shfl_xor(part, off);
    if (lane == 0) out[b] = 1.f / (1.f + __expf(-part));
  }
}

extern "C" void kernel_launch(void* const* d_in, const int* in_sizes, int n_in,
                              void* d_out, int out_size, void* d_ws, size_t ws_size,
                              hipStream_t stream) {
  const int*   items  = (const int*)d_in[1];
  const int*   user_h = (const int*)d_in[2];
  const int*   user_r = (const int*)d_in[3];
  const int*   user_t = (const int*)d_in[4];
  const int*   item_h = (const int*)d_in[5];
  const int*   item_r = (const int*)d_in[6];
  const int*   item_t = (const int*)d_in[7];
  const float* ent    = (const float*)d_in[8];
  const float* rel    = (const float*)d_in[9];
  const float* W1     = (const float*)d_in[10];
  const float* W2     = (const float*)d_in[11];
  const float* w3     = (const float*)d_in[12];
  const float* G1     = (const float*)d_in[13];
  const float* G2     = (const float*)d_in[14];
  __bf16* wsb = (__bf16*)d_ws;   // 48 KB used
  float* out = (float*)d_out;

  prep_w<<<dim3(48), dim3(256), 0, stream>>>(W1, G1, W2, G2, wsb);
  ckan_fast<<<dim3(NB), dim3(256), 0, stream>>>(
      items, user_h, user_r, user_t, item_h, item_r, item_t,
      ent, rel, wsb, w3, out);
}

// Round 8
// 142.647 us; speedup vs baseline: 1.2655x; 1.1463x over previous
//
#include <hip/hip_runtime.h>

#define DIM 64
#define NB 4096
#define NTOK 32
#define BPB 8     // batch elements per block

typedef __attribute__((ext_vector_type(8))) __bf16 bf16x8;
typedef __attribute__((ext_vector_type(4))) float f32x4;

__device__ __forceinline__ f32x4 mfma16(bf16x8 a, bf16x8 b, f32x4 c) {
  return __builtin_amdgcn_mfma_f32_16x16x32_bf16(a, b, c, 0, 0, 0);
}

// LDS XOR swizzle: keeps 16B blocks contiguous, bank conflicts measured 0.
#define SWC(row, col) ((col) ^ (((row) & 7) << 3))

// Transpose weights to bf16 [col][k] in ws (48 KB):
// W1t[64][128], G1t[64][128], W2t[64][64], G2t[64][64]
__global__ void prep_w(const float* __restrict__ W1, const float* __restrict__ G1,
                       const float* __restrict__ W2, const float* __restrict__ G2,
                       __bf16* __restrict__ ws) {
  int i = blockIdx.x * 256 + threadIdx.x;
  if (i < 8192) {
    int c = i >> 7, k = i & 127;
    ws[i]        = (__bf16)W1[k * 64 + c];
    ws[8192 + i] = (__bf16)G1[k * 64 + c];
  } else if (i < 12288) {
    int j = i - 8192;
    int c = j >> 6, k = j & 63;
    ws[16384 + j] = (__bf16)W2[k * 64 + c];
    ws[20480 + j] = (__bf16)G2[k * 64 + c];
  }
}

// R8: block = BPB(8) batch elements; 4 waves = 4 (l,tower) combos, each
// iterating over the 8 b's (independent chains -> ILP). 512 blocks = 2/CU =
// whole grid resident. Depth-1 index prefetch + early t_e issue raise per-wave
// outstanding loads ~3x (R7 post-mortem: gather stream was latency*concurrency
// limited at ~0.7 TB/s). #pragma unroll 1 on the it-loop: 8x unroll would blow
// the register file (R2/R3: forced low-VGPR -> 184-547 MB scratch storms; keep
// plain __launch_bounds__(256), no min-waves arg).
__global__ __launch_bounds__(256) void ckan_fast(
    const int* __restrict__ items, const int* __restrict__ user_h,
    const int* __restrict__ user_r, const int* __restrict__ user_t,
    const int* __restrict__ item_h, const int* __restrict__ item_r,
    const int* __restrict__ item_t,
    const float* __restrict__ ent, const float* __restrict__ rel,
    const __bf16* __restrict__ wsb, const float* __restrict__ w3,
    float* __restrict__ out)
{
  __shared__ __align__(16) __bf16 buf[128][64];     // 16 KB, wave-private rows
  __shared__ float outbuf[BPB][4][64];               // 8 KB
  __shared__ float pu_lds[BPB];                      // 32 B

  const int tid  = threadIdx.x;
  const int w    = tid >> 6;      // combo: l = w>>1, tower = w&1
  const int lane = tid & 63;
  const int r16  = lane & 15;
  const int g4   = lane >> 4;
  const int rb   = w * 32;        // wave-private LDS rows
  const int b0   = blockIdx.x * BPB;
  const int l    = w >> 1;
  const int tower = w & 1;

  const __bf16* __restrict__ W1t = wsb;
  const __bf16* __restrict__ G1t = wsb + 8192;
  const __bf16* __restrict__ W2t = wsb + 16384;
  const __bf16* __restrict__ G2t = wsb + 20480;

  const int* __restrict__ Hp = tower ? item_h : user_h;
  const int* __restrict__ Rp = tower ? item_r : user_r;
  const int* __restrict__ Tp = tower ? item_t : user_t;

  float w3c[4];
#pragma unroll
  for (int n = 0; n < 4; ++n) w3c[n] = w3[n * 16 + r16];

  const f32x4 zero4 = {0.f, 0.f, 0.f, 0.f};

  // ---- prologue: indices for it=0 ----
  int ib = (l * NB + b0) * NTOK;
  int h0  = Hp[ib + r16] * DIM,      h1  = Hp[ib + 16 + r16] * DIM;
  int rr0 = Rp[ib + r16] * DIM,      rr1 = Rp[ib + 16 + r16] * DIM;
  int t0  = Tp[ib + r16] * DIM,      t1  = Tp[ib + 16 + r16] * DIM;
  int ioidx = items[b0] * DIM;

#pragma unroll 1
  for (int it = 0; it < BPB; ++it) {
    // ---- issue CUR A-gathers (f32, 16 x 16B) ----
    f32x4 axlo[4][2], axhi[4][2];
#pragma unroll
    for (int kk = 0; kk < 4; ++kk)
#pragma unroll
      for (int m = 0; m < 2; ++m) {
        const float* src = (kk < 2)
            ? ent + (m ? h1 : h0) + kk * 32 + g4 * 8
            : rel + (m ? rr1 : rr0) + (kk - 2) * 32 + g4 * 8;
        axlo[kk][m] = *(const f32x4*)(src);
        axhi[kk][m] = *(const f32x4*)(src + 4);
      }
    // wave0: io row for this b (4 x 16B, overlaps everything below)
    f32x4 io0l = zero4, io0h = zero4, io1l = zero4, io1h = zero4;
    if (w == 0) {
      io0l = *(const f32x4*)(ent + ioidx + g4 * 8);
      io0h = *(const f32x4*)(ent + ioidx + g4 * 8 + 4);
      io1l = *(const f32x4*)(ent + ioidx + 32 + g4 * 8);
      io1h = *(const f32x4*)(ent + ioidx + 32 + g4 * 8 + 4);
    }

    // ---- issue NEXT indices (depth-1 prefetch) ----
    int h0n = h0, h1n = h1, rr0n = rr0, rr1n = rr1, t0n = t0, t1n = t1, ion = ioidx;
    if (it + 1 < BPB) {
      const int ibn = ib + NTOK;
      h0n  = Hp[ibn + r16] * DIM;      h1n  = Hp[ibn + 16 + r16] * DIM;
      rr0n = Rp[ibn + r16] * DIM;      rr1n = Rp[ibn + 16 + r16] * DIM;
      t0n  = Tp[ibn + r16] * DIM;      t1n  = Tp[ibn + 16 + r16] * DIM;
      ion  = items[b0 + it + 1] * DIM;
      ib = ibn;
    }

    // wave0: user-origin partial from the raw f32 x-rows (layer0/user combo)
    float uo[2][8];
    if (w == 0) {
#pragma unroll
      for (int kk = 0; kk < 2; ++kk)
#pragma unroll
        for (int j = 0; j < 4; ++j) {
          uo[kk][j]     = axlo[kk][0][j] + axlo[kk][1][j];
          uo[kk][4 + j] = axhi[kk][0][j] + axhi[kk][1][j];
        }
    }

    // cvt to bf16 fragments
    bf16x8 afr[4][2];
#pragma unroll
    for (int kk = 0; kk < 4; ++kk)
#pragma unroll
      for (int m = 0; m < 2; ++m) {
        bf16x8 a;
#pragma unroll
        for (int j = 0; j < 4; ++j) {
          a[j]     = (__bf16)axlo[kk][m][j];
          a[4 + j] = (__bf16)axhi[kk][m][j];
        }
        afr[kk][m] = a;
      }

    // ---- GEMM1 (combined S+G): x[32,128] @ {W1,G1}[128,64] ----
    f32x4 accS[2][4], accG[2][4];
#pragma unroll
    for (int m = 0; m < 2; ++m)
#pragma unroll
      for (int n = 0; n < 4; ++n) { accS[m][n] = zero4; accG[m][n] = zero4; }
#pragma unroll
    for (int kk = 0; kk < 4; ++kk)
#pragma unroll
      for (int n = 0; n < 4; ++n) {
        bf16x8 bS = *(const bf16x8*)(W1t + (n * 16 + r16) * 128 + kk * 32 + g4 * 8);
        bf16x8 bG = *(const bf16x8*)(G1t + (n * 16 + r16) * 128 + kk * 32 + g4 * 8);
#pragma unroll
        for (int m = 0; m < 2; ++m) {
          accS[m][n] = mfma16(afr[kk][m], bS, accS[m][n]);
          accG[m][n] = mfma16(afr[kk][m], bG, accG[m][n]);
        }
      }

    // ---- issue t_e gathers now (consumed ~2000cy later at the epilogue) ----
    f32x4 telo[2][2], tehi[2][2];
#pragma unroll
    for (int m2 = 0; m2 < 2; ++m2)
#pragma unroll
      for (int h = 0; h < 2; ++h) {
        const float* ts = ent + (m2 ? t1 : t0) + h * 32 + g4 * 8;
        telo[m2][h] = *(const f32x4*)(ts);
        tehi[m2][h] = *(const f32x4*)(ts + 4);
      }

    // ---- S path: relu(s1) -> buf -> GEMM2-S -> att ----
#pragma unroll
    for (int m = 0; m < 2; ++m)
#pragma unroll
      for (int n = 0; n < 4; ++n)
#pragma unroll
        for (int i = 0; i < 4; ++i) {
          const int row = rb + m * 16 + g4 * 4 + i;
          const int col = n * 16 + r16;
          buf[row][SWC(row, col)] = (__bf16)fmaxf(accS[m][n][i], 0.f);
        }

    f32x4 acc2S[2][4];
#pragma unroll
    for (int m = 0; m < 2; ++m)
#pragma unroll
      for (int n = 0; n < 4; ++n) acc2S[m][n] = zero4;
#pragma unroll
    for (int kk = 0; kk < 2; ++kk) {
      bf16x8 aS[2];
#pragma unroll
      for (int m = 0; m < 2; ++m) {
        const int tok = rb + m * 16 + r16;
        aS[m] = *(const bf16x8*)&buf[tok][SWC(tok, kk * 32 + g4 * 8)];
      }
#pragma unroll
      for (int n = 0; n < 4; ++n) {
        bf16x8 bS = *(const bf16x8*)(W2t + (n * 16 + r16) * 64 + kk * 32 + g4 * 8);
#pragma unroll
        for (int m = 0; m < 2; ++m) acc2S[m][n] = mfma16(aS[m], bS, acc2S[m][n]);
      }
    }

    // s3 + softmax (no max pass: scores are sigmoids in (0,1))
    float att[2][4];
    {
      float dotp[2][4];
#pragma unroll
      for (int m = 0; m < 2; ++m)
#pragma unroll
        for (int i = 0; i < 4; ++i) {
          float d = 0.f;
#pragma unroll
          for (int n = 0; n < 4; ++n)
            d += fmaxf(acc2S[m][n][i], 0.f) * w3c[n];
          dotp[m][i] = d;
        }
#pragma unroll
      for (int off = 1; off <= 8; off <<= 1)
#pragma unroll
        for (int m = 0; m < 2; ++m)
#pragma unroll
          for (int i = 0; i < 4; ++i)
            dotp[m][i] += __shfl_xor(dotp[m][i], off);
      float den = 0.f;
#pragma unroll
      for (int m = 0; m < 2; ++m)
#pragma unroll
        for (int i = 0; i < 4; ++i) {
          const float sc = 1.f / (1.f + __expf(-dotp[m][i]));
          att[m][i] = __expf(sc);
          den += att[m][i];
        }
      den += __shfl_xor(den, 16);
      den += __shfl_xor(den, 32);
      const float inv = 1.f / den;
#pragma unroll
      for (int m = 0; m < 2; ++m)
#pragma unroll
        for (int i = 0; i < 4; ++i) att[m][i] *= inv;
    }

    // ---- G path: relu(g1) -> buf (reuse) -> GEMM2-G ----
#pragma unroll
    for (int m = 0; m < 2; ++m)
#pragma unroll
      for (int n = 0; n < 4; ++n)
#pragma unroll
        for (int i = 0; i < 4; ++i) {
          const int row = rb + m * 16 + g4 * 4 + i;
          const int col = n * 16 + r16;
          buf[row][SWC(row, col)] = (__bf16)fmaxf(accG[m][n][i], 0.f);
        }

    f32x4 acc2G[2][4];
#pragma unroll
    for (int m = 0; m < 2; ++m)
#pragma unroll
      for (int n = 0; n < 4; ++n) acc2G[m][n] = zero4;
#pragma unroll
    for (int kk = 0; kk < 2; ++kk) {
      bf16x8 aG[2];
#pragma unroll
      for (int m = 0; m < 2; ++m) {
        const int tok = rb + m * 16 + r16;
        aG[m] = *(const bf16x8*)&buf[tok][SWC(tok, kk * 32 + g4 * 8)];
      }
#pragma unroll
      for (int n = 0; n < 4; ++n) {
        bf16x8 bG = *(const bf16x8*)(G2t + (n * 16 + r16) * 64 + kk * 32 + g4 * 8);
#pragma unroll
        for (int m = 0; m < 2; ++m) acc2G[m][n] = mfma16(aG[m], bG, acc2G[m][n]);
      }
    }

    // ---- epilogue: p = att * 2*sigmoid(g2) -> buf; dot with t_e fragments ----
#pragma unroll
    for (int m = 0; m < 2; ++m)
#pragma unroll
      for (int n = 0; n < 4; ++n)
#pragma unroll
        for (int i = 0; i < 4; ++i) {
          const int row = rb + m * 16 + g4 * 4 + i;
          const int col = n * 16 + r16;
          const float g2v = 2.f / (1.f + __expf(-acc2G[m][n][i]));
          buf[row][SWC(row, col)] = (__bf16)(att[m][i] * g2v);
        }

    float dsum[2][8];
#pragma unroll
    for (int h = 0; h < 2; ++h)
#pragma unroll
      for (int j = 0; j < 8; ++j) dsum[h][j] = 0.f;

#pragma unroll
    for (int m2 = 0; m2 < 2; ++m2) {
      const int prow = rb + m2 * 16 + r16;
#pragma unroll
      for (int h = 0; h < 2; ++h) {
        bf16x8 pf = *(const bf16x8*)&buf[prow][SWC(prow, h * 32 + g4 * 8)];
#pragma unroll
        for (int j = 0; j < 4; ++j) {
          dsum[h][j]     += (float)pf[j]     * telo[m2][h][j];
          dsum[h][4 + j] += (float)pf[4 + j] * tehi[m2][h][j];
        }
      }
    }
#pragma unroll
    for (int off = 1; off <= 8; off <<= 1)
#pragma unroll
      for (int h = 0; h < 2; ++h)
#pragma unroll
        for (int j = 0; j < 8; ++j)
          dsum[h][j] += __shfl_xor(dsum[h][j], off);
    if (r16 == 0) {
#pragma unroll
      for (int h = 0; h < 2; ++h)
#pragma unroll
        for (int j = 0; j < 8; ++j)
          outbuf[it][w][h * 32 + g4 * 8 + j] = dsum[h][j];
    }

    // ---- wave0: partU = (mean_t u_h0) . io  (dot first, then 6 shuffles) ----
    if (w == 0) {
      float s = 0.f;
#pragma unroll
      for (int j = 0; j < 4; ++j) {
        s += uo[0][j] * io0l[j] + uo[0][4 + j] * io0h[j];
        s += uo[1][j] * io1l[j] + uo[1][4 + j] * io1h[j];
      }
      s *= (1.f / 32.f);
#pragma unroll
      for (int off = 1; off <= 32; off <<= 1) s += __shfl_xor(s, off);
      if (lane == 0) pu_lds[it] = s;
    }

    // rotate prefetched indices
    h0 = h0n; h1 = h1n; rr0 = rr0n; rr1 = rr1n; t0 = t0n; t1 = t1n; ioidx = ion;
  }

  __syncthreads();

  // ---- final combine: wave0 scores all BPB elements ----
  if (w == 0) {
#pragma unroll 1
    for (int bb = 0; bb < BPB; ++bb) {
      float part = outbuf[bb][0][lane] * outbuf[bb][1][lane]
                 + outbuf[bb][2][lane] * outbuf[bb][3][lane];
#pragma unroll
      for (int off = 32; off >= 1; off >>= 1) part += __shfl_xor(part, off);
      if (lane == 0) out[b0 + bb] = 1.f / (1.f + __expf(-(part + pu_lds[bb])));
    }
  }
}

extern "C" void kernel_launch(void* const* d_in, const int* in_sizes, int n_in,
                              void* d_out, int out_size, void* d_ws, size_t ws_size,
                              hipStream_t stream) {
  const int*   items  = (const int*)d_in[1];
  const int*   user_h = (const int*)d_in[2];
  const int*   user_r = (const int*)d_in[3];
  const int*   user_t = (const int*)d_in[4];
  const int*   item_h = (const int*)d_in[5];
  const int*   item_r = (const int*)d_in[6];
  const int*   item_t = (const int*)d_in[7];
  const float* ent    = (const float*)d_in[8];
  const float* rel    = (const float*)d_in[9];
  const float* W1     = (const float*)d_in[10];
  const float* W2     = (const float*)d_in[11];
  const float* w3     = (const float*)d_in[12];
  const float* G1     = (const float*)d_in[13];
  const float* G2     = (const float*)d_in[14];
  __bf16* wsb = (__bf16*)d_ws;   // 48 KB used
  float* out = (float*)d_out;

  prep_w<<<dim3(48), dim3(256), 0, stream>>>(W1, G1, W2, G2, wsb);
  ckan_fast<<<dim3(NB / BPB), dim3(256), 0, stream>>>(
      items, user_h, user_r, user_t, item_h, item_r, item_t,
      ent, rel, wsb, w3, out);
}